// Round 9
// baseline (220.228 us; speedup 1.0000x reference)
//
#include <hip/hip_runtime.h>
#include <hip/hip_bf16.h>

#define NB 128        // batch B
#define NMEM 100000   // N
#define ND 128        // D
constexpr float K2 = 20.6099442241331655f;   // log2(e)/T  (T=0.07)

constexpr int LROW = ND + 8;              // xs LDS row: 136 bf16 = 272 B
constexpr int NTP = NMEM / 32;            // 3125 pair-tiles of 32 n-cols (exact)
constexpr int GRID = 512;                 // 2 blocks/CU persistent (R4 measured-best)
constexpr int NWAVES = GRID * 4;          // 2048
constexpr int ZSTRIDE = 16;               // zbuf slots 64 B apart
constexpr int RGRID = 2048;               // rescale grid

typedef __attribute__((ext_vector_type(8))) __bf16 bf16x8;
typedef __attribute__((ext_vector_type(4))) float f32x4;
struct bf4 { __bf16 a, b, c, d; };

// A = mem rows (n), B = x rows (b).
// A-frag: A[n=lane&15][k=q*8+j]; B-frag: B[b=lane&15][k=q*8+j]
// C/D: col(b)=lane&15, row(n)=q*4+r   [HW-verified m89/m91]
// R4's measured-best pass1 (43us) VERBATIM in structure, plus exp2 stores:
//  - mask: nontemporal (never re-read)
//  - exp:  TEMPORAL, 128B-line-complete bursts -> L2/L3 retention for rescale
// Z accumulated from the same exp values. Normalization via streaming rescale.
__global__ __launch_bounds__(256, 2) void nce_pass1(
    const float* __restrict__ x,
    const int* __restrict__ labels,
    const float* __restrict__ mem_da,
    float* __restrict__ zbuf,
    float* __restrict__ expout,
    float* __restrict__ maskout)
{
  __shared__ __bf16 xs[NB * LROW];   // 34816 B
  __shared__ float aux[NB];          // lbl_b
  __shared__ float zl[NB];           // block Z partials

  const int tid = threadIdx.x;

  // ---- one-time stage: x -> bf16 LDS ----
  const float4* x4 = (const float4*)x;
  #pragma unroll
  for (int c = 0; c < 4; ++c) {
    float4 xv[4];
    #pragma unroll
    for (int i = 0; i < 4; ++i) xv[i] = x4[tid + (c * 4 + i) * 256];
    #pragma unroll
    for (int i = 0; i < 4; ++i) {
      int g4 = tid + (c * 4 + i) * 256;
      *(bf4*)&xs[(g4 >> 5) * LROW + (g4 & 31) * 4] =
          bf4{(__bf16)xv[i].x, (__bf16)xv[i].y, (__bf16)xv[i].z, (__bf16)xv[i].w};
    }
  }
  if (tid < NB) { aux[tid] = (float)labels[tid]; zl[tid] = 0.f; }
  __syncthreads();                   // the ONLY barrier before finalize

  const int wid = tid >> 6, lane = tid & 63, q = lane >> 4, l16 = lane & 15;
  const int wgid = blockIdx.x * 4 + wid;

  // per-lane b-row constants: b = mt*16 + l16
  float lblb[8];
  #pragma unroll
  for (int mt = 0; mt < 8; ++mt) lblb[mt] = aux[mt * 16 + l16];

  float zacc[8];
  #pragma unroll
  for (int mt = 0; mt < 8; ++mt) zacc[mt] = 0.f;

  // ---- barrier-free wave loop over 32-col pair-tiles (1-2 per wave) ----
  for (int t = wgid; t < NTP; t += NWAVES) {
    f32x4 acc[2][8];                 // batch ALL 64 MFMAs before any store (R4)
    float ln[2];

    #pragma unroll
    for (int h = 0; h < 2; ++h) {
      const float* rowp = mem_da + (size_t)(t * 32 + h * 16 + l16) * 129;
      ln[h] = rowp[0];               // bank label

      bf16x8 ab[4];
      #pragma unroll
      for (int kc = 0; kc < 4; ++kc) {
        float tmp[8];
        __builtin_memcpy(tmp, rowp + 1 + kc * 32 + q * 8, 32);
        #pragma unroll
        for (int j = 0; j < 8; ++j) ab[kc][j] = (__bf16)tmp[j];
      }

      #pragma unroll
      for (int mt = 0; mt < 8; ++mt) acc[h][mt] = (f32x4){0.f, 0.f, 0.f, 0.f};
      #pragma unroll
      for (int kc = 0; kc < 4; ++kc) {
        const int ko = kc * 32 + q * 8;
        #pragma unroll
        for (int mt = 0; mt < 8; ++mt) {
          bf16x8 xb = *(const bf16x8*)&xs[(mt * 16 + l16) * LROW + ko];
          acc[h][mt] = __builtin_amdgcn_mfma_f32_16x16x32_bf16(ab[kc], xb, acc[h][mt], 0, 0, 0);
        }
      }
    }

    // labels of the 32 n-rows live in lanes 0..15 of each 16-group
    float ml[2][4];
    #pragma unroll
    for (int h = 0; h < 2; ++h)
      #pragma unroll
      for (int r = 0; r < 4; ++r) ml[h][r] = __shfl(ln[h], q * 4 + r, 16);

    // ---- store burst: per row, both 64B halves back-to-back per buffer ----
    #pragma unroll
    for (int mt = 0; mt < 8; ++mt) {
      const size_t base = (size_t)(mt * 16 + l16) * NMEM + t * 32 + q * 4;
      f32x4 mk0, mk1, e0, e1;
      float zs = 0.f;
      #pragma unroll
      for (int r = 0; r < 4; ++r) {
        e0[r] = exp2f(acc[0][mt][r] * K2);
        e1[r] = exp2f(acc[1][mt][r] * K2);
        zs += e0[r] + e1[r];
        mk0[r] = (ml[0][r] == lblb[mt]) ? 1.0f : 0.0f;
        mk1[r] = (ml[1][r] == lblb[mt]) ? 1.0f : 0.0f;
      }
      zacc[mt] += zs;
      __builtin_nontemporal_store(mk0, (f32x4*)&maskout[base]);
      __builtin_nontemporal_store(mk1, (f32x4*)&maskout[base + 16]);
      *(f32x4*)&expout[base]      = e0;   // temporal: L2/L3 retention for rescale
      *(f32x4*)&expout[base + 16] = e1;
    }
  }

  // ---- finalize: reduce over q-lanes (xor 16, 32) -> LDS -> global ----
  #pragma unroll
  for (int mt = 0; mt < 8; ++mt) {
    float v = zacc[mt];
    v += __shfl_xor(v, 16);
    v += __shfl_xor(v, 32);
    if (lane < 16) atomicAdd(&zl[mt * 16 + lane], v);
  }
  __syncthreads();
  if (tid < NB) atomicAdd(&zbuf[tid * ZSTRIDE], zl[tid]);
}

// out[b][n] *= 1/Z[b] — pure coalesced stream (~102MB r+w, read mostly L3-hot)
__global__ __launch_bounds__(256) void rescale(
    float* __restrict__ out, const float* __restrict__ zbuf)
{
  __shared__ float sinv[NB];
  if (threadIdx.x < NB) sinv[threadIdx.x] = 1.0f / zbuf[threadIdx.x * ZSTRIDE];
  __syncthreads();

  constexpr int TOT4 = NB * NMEM / 4;      // 3,200,000 float4
  constexpr int ROW4 = NMEM / 4;           // 25,000 float4 per row
  const int stride = RGRID * 256;
  for (int i = blockIdx.x * 256 + threadIdx.x; i < TOT4; i += stride) {
    const float s = sinv[i / ROW4];
    f32x4 v = *((const f32x4*)out + i);
    v[0] *= s; v[1] *= s; v[2] *= s; v[3] *= s;
    __builtin_nontemporal_store(v, (f32x4*)out + i);
  }
}

extern "C" void kernel_launch(void* const* d_in, const int* in_sizes, int n_in,
                              void* d_out, int out_size, void* d_ws, size_t ws_size,
                              hipStream_t stream) {
  const float* x      = (const float*)d_in[0];
  const int* labels   = (const int*)d_in[2];
  const float* mem_da = (const float*)d_in[3];
  float* out     = (float*)d_out;
  float* maskout = out + (size_t)NB * NMEM;
  float* zbuf    = (float*)d_ws;     // 128*16 floats = 8192 B

  hipMemsetAsync(zbuf, 0, NB * ZSTRIDE * sizeof(float), stream);
  nce_pass1<<<GRID, 256, 0, stream>>>(x, labels, mem_da, zbuf, out, maskout);
  rescale<<<RGRID, 256, 0, stream>>>(out, zbuf);
}